// Round 4
// baseline (1653.786 us; speedup 1.0000x reference)
//
#include <hip/hip_runtime.h>

// NeuralODE SSP-RK3, z:[32,16,8192] fp32, W:[16,16,5], 100 steps, h=t/100.
// R15: interior fused to ONE 61-tap conv (z' = z + S5 z) - passed, but
// dispatch stayed ~38us: the 2 edge blocks' 15-stage barrier chain set the
// dispatch time (latency-chain invariant, R14 lesson).
// R16 CHANGE: edges are linear too. The 5-step clamped update on the
// contaminated cols (37/side) is a fixed map out = x + C*x_win with
// C = (M-I) in R^{592x1072}. Build C_L/C_R on device ONCE by evolving the
// 1072 basis vectors through the verified 15-stage MFMA stage code (2144
// independent small blocks, 96-col private windows - no global chain).
// Steady state is then uniform single-stage: 64 fused-conv blocks (edge
// blocks skip contaminated-col stores) + 4 small GEMV blocks per batch
// (fp32 C, L2-streamed, ~5us, hidden under interior ~12us).
// Predicted: dispatch 38 -> 12-16us, total 801 -> ~400us, absmax ~same.

#define NCH    16
#define LL     8192
#define TX     128
#define NBX    64
#define NB     32
#define NSTEPS 100
#define SPK    5
#define NKER   (NSTEPS / SPK)

#define RAD    30           // fused-operator radius = 6*SPK
#define NCHUNK 31           // 62 taps (61 real + 1 zero pad) / 2 per K-chunk
#define ISLAB  190          // interior slab cols: o(0..127)+k(0..61) -> 0..188

#define WCOLS  96           // edge-operator build window (6 MFMA tiles)
#define DWIN   1072         // 67 cols x 16 ch operator input dim
#define NROWS  592          // 37 cols x 16 ch contaminated outputs
#define EBLK   4            // runtime edge-fix blocks per batch (2 per side)

typedef __bf16 bf16x8 __attribute__((ext_vector_type(8)));
typedef __bf16 bf16x4 __attribute__((ext_vector_type(4)));
typedef float  f32x4  __attribute__((ext_vector_type(4)));

// ---- setup: conv-kernel algebra in __device__ globals (fp32) ----
__device__ __align__(16) float g_G [ 5*256];   // h*F
__device__ __align__(16) float g_G2[ 9*256];   // G^2
__device__ __align__(16) float g_Tp[13*256];   // first G^3, then T'
__device__ __align__(16) float g_T2[25*256];   // T'^2
__device__ __align__(16) float g_T3[37*256];   // T'^3
__device__ __align__(16) float g_T4[49*256];   // T'^4
__device__ __align__(16) float g_T5[61*256];   // T'^5
__device__ __align__(16) __bf16 g_Sfrag[NCHUNK*64*8];  // A-frag table [c][lane][8]
__device__ __align__(16) float g_CL[(size_t)NROWS*DWIN];  // left  edge: M - I
__device__ __align__(16) float g_CR[(size_t)NROWS*DWIN];  // right edge: M - I

__global__ void build_G(const float* __restrict__ W, const int* __restrict__ tptr) {
  const float h = (float)(*tptr) / (float)NSTEPS;
  const int o = threadIdx.x >> 4, i = threadIdx.x & 15;
#pragma unroll
  for (int k = 0; k < 5; ++k)
    g_G[k*256 + o*16 + i] = h * W[o*80 + i*5 + k];
}

// C_d = sum_{a+b=d} A_a * B_b (16x16 matrix product per pair). grid.x = 2*(ra+rb)+1.
__global__ void compose_k(int mode) {
  const float* A; int ra; const float* B; int rb; float* C;
  switch (mode) {
    case 0:  A = g_G;  ra = 2;  B = g_G;  rb = 2; C = g_G2; break; //  9 taps
    case 1:  A = g_G2; ra = 4;  B = g_G;  rb = 2; C = g_Tp; break; // G^3, 13
    case 2:  A = g_Tp; ra = 6;  B = g_Tp; rb = 6; C = g_T2; break; // 25
    case 3:  A = g_T2; ra = 12; B = g_Tp; rb = 6; C = g_T3; break; // 37
    case 4:  A = g_T3; ra = 18; B = g_Tp; rb = 6; C = g_T4; break; // 49
    default: A = g_T4; ra = 24; B = g_Tp; rb = 6; C = g_T5; break; // 61
  }
  const int rc = ra + rb;
  const int d = (int)blockIdx.x - rc;
  const int o = threadIdx.x >> 4, i = threadIdx.x & 15;
  float acc = 0.f;
  for (int a = -ra; a <= ra; ++a) {
    const int b = d - a;
    if (b < -rb || b > rb) continue;
    const float* Am = A + (a+ra)*256 + o*16;
    const float* Bm = B + (b+rb)*256 + i;
#pragma unroll
    for (int j = 0; j < 16; ++j) acc += Am[j] * Bm[j*16];
  }
  C[(size_t)blockIdx.x*256 + o*16 + i] = acc;
}

__global__ void build_Tp() {   // g_Tp holds G^3; T' = G^3/6 + pad(G2)/2 + pad(G)
  const int o = threadIdx.x >> 4, i = threadIdx.x & 15;
#pragma unroll
  for (int k = 0; k < 13; ++k) {
    const int d = k - 6;
    float v = g_Tp[k*256 + o*16 + i] * (1.f/6.f);
    if (d >= -4 && d <= 4) v += 0.5f * g_G2[(d+4)*256 + o*16 + i];
    if (d >= -2 && d <= 2) v += g_G[(d+2)*256 + o*16 + i];
    g_Tp[k*256 + o*16 + i] = v;
  }
}

__device__ __forceinline__ float padread(const float* M, int r, int d, int oi) {
  return (d >= -r && d <= r) ? M[(d+r)*256 + oi] : 0.f;
}

// S5 = 5T' + 10T'^2 + 10T'^3 + 5T'^4 + T'^5, packed as bf16 MFMA A-frags.
__global__ void pack_S() {
  const int c = blockIdx.x;
  const int lane = threadIdx.x & 63;
  const int jj = (threadIdx.x >> 6) * 2;
  const int gg = lane >> 4, n = lane & 15;
  const int k = 2*c + (gg >> 1);
  const int d = k - RAD;
#pragma unroll
  for (int u = 0; u < 2; ++u) {
    const int j = jj + u;
    const int i = (gg & 1)*8 + j;
    const int oi = n*16 + i;
    float v = 0.f;
    if (k <= 60) {
      v = 5.f  * padread(g_Tp,  6, d, oi)
        + 10.f * padread(g_T2, 12, d, oi)
        + 10.f * padread(g_T3, 18, d, oi)
        + 5.f  * padread(g_T4, 24, d, oi)
        +        padread(g_T5, 30, d, oi);
    }
    g_Sfrag[((size_t)c*64 + lane)*8 + j] = (__bf16)v;
  }
}

// ---- shared helpers ----
__device__ __forceinline__ int ldsIdx(int col, int ch) {
  return col * NCH + (ch ^ ((col & 4) << 1));
}

__device__ __forceinline__ bf16x8 mkA(const float* __restrict__ W, int c, int g, int n) {
  const int kk = c * 2 + (g >> 1);
  bf16x8 a;
#pragma unroll
  for (int j = 0; j < 8; ++j) {
    const int i = (g & 1) * 8 + j;
    a[j] = (__bf16)((kk < 5) ? W[n * (NCH * 5) + i * 5 + kk] : 0.0f);
  }
  return a;
}

// ---- edge operator build: evolve basis vector j through 15 stages ----
// Block = 6 waves, one 96-col window; e=0 left (window col = global col),
// e=1 right (window col w = global LL-96+w). Basis: left j <-> (col j>>4,
// ch j&15); right j <-> (col 29+(j>>4), ch j&15). Exact same MFMA stage
// code as the verified 15-stage path; BC shuffle at t=0 (left) / t=5 (right).
__global__ __launch_bounds__(384)
void edge_evolve(const float* __restrict__ W, const int* __restrict__ tptr) {
  __shared__ __align__(16) __bf16 ES[2][WCOLS * NCH];
  const int j = blockIdx.x, e = blockIdx.y;
  const float h = (float)(*tptr) / (float)NSTEPS;
  const int tid = threadIdx.x, lane = tid & 63, wv = tid >> 6;  // wv 0..5
  const int g = lane >> 4, n = lane & 15;
  const int t = wv, mycol = 16 * t + n;
  const int cwj = (e ? 29 : 0) + (j >> 4), chj = j & 15;

  const bf16x8 af0 = mkA(W, 0, g, n);
  const bf16x8 af1 = mkA(W, 1, g, n);
  const bf16x8 af2 = mkA(W, 2, g, n);

  const int hot = ldsIdx(cwj, chj);
  for (int q = tid; q < WCOLS * NCH; q += 384)
    ES[0][q] = (__bf16)(q == hot ? 1.f : 0.f);

  f32x4 kz = {0.f, 0.f, 0.f, 0.f};
  if (mycol == cwj && g == (chj >> 2)) kz[chj & 3] = 1.f;
  f32x4 kf = {0.f, 0.f, 0.f, 0.f};
  __syncthreads();

  const float c13 = 1.0f / 3.0f, c23 = 2.0f / 3.0f;
  int rb = 0;
#pragma unroll 1
  for (int sp = 0; sp < SPK; ++sp) {
#pragma unroll 1
    for (int st = 0; st < 3; ++st) {
      const float az  = (st == 0) ? 1.0f : (st == 1) ? 0.75f : c13;
      const float ak  = (st == 0) ? 0.0f : (st == 1) ? 0.25f : c23;
      const float agh = (st == 0) ? h    : (st == 1) ? 0.25f*h : c23*h;
      const __bf16* RS = ES[rb];
      __bf16* WS = ES[rb ^ 1];
      f32x4 acc = {0.f, 0.f, 0.f, 0.f};
#pragma unroll
      for (int c = 0; c < 3; ++c) {
        const int kk = c * 2 + (g >> 1);
        int s = mycol + kk - 2;
        s = min(max(s, 0), WCOLS - 1);   // pad only affects overwritten/garbage cols
        const bf16x8 bfrag = *(const bf16x8*)(&RS[ldsIdx(s, (g & 1) * 8)]);
        const bf16x8 a = (c == 0) ? af0 : (c == 1) ? af1 : af2;
        acc = __builtin_amdgcn_mfma_f32_16x16x32_bf16(a, bfrag, acc, 0, 0, 0);
      }
      f32x4 v;
#pragma unroll
      for (int r = 0; r < 4; ++r) v[r] = az * kz[r] + ak * kf[r] + agh * acc[r];
      if (e == 0 && t == 0) {            // cols 0..9 <- col 10
#pragma unroll
        for (int r = 0; r < 4; ++r) {
          const float sv = __shfl(v[r], (lane & 48) | 10, 64);
          if (n < 10) v[r] = sv;
        }
      }
      if (e == 1 && t == 5) {            // window cols 86..95 <- 85 (n=5)
#pragma unroll
        for (int r = 0; r < 4; ++r) {
          const float sv = __shfl(v[r], (lane & 48) | 5, 64);
          if (n > 5) v[r] = sv;
        }
      }
      kf = v;
      if (st == 2) kz = v;
      bf16x4 bv = { (__bf16)v[0], (__bf16)v[1], (__bf16)v[2], (__bf16)v[3] };
      *(bf16x4*)(&WS[ldsIdx(mycol, g * 4)]) = bv;
      __syncthreads();
      rb ^= 1;
    }
  }

  // extract contaminated rows of (M - I)
  if (e == 0) {
    if (mycol <= 36) {
      const int rowb = mycol * 16 + g * 4;
#pragma unroll
      for (int r = 0; r < 4; ++r) {
        const float id = (mycol == cwj && (g * 4 + r) == chj) ? 1.f : 0.f;
        g_CL[(size_t)(rowb + r) * DWIN + j] = kz[r] - id;
      }
    }
  } else {
    if (mycol >= 59) {                   // window 59..95 = global LL-37..LL-1
      const int rowb = (mycol - 59) * 16 + g * 4;
#pragma unroll
      for (int r = 0; r < 4; ++r) {
        const float id = (mycol == cwj && (g * 4 + r) == chj) ? 1.f : 0.f;
        g_CR[(size_t)(rowb + r) * DWIN + j] = kz[r] - id;
      }
    }
  }
}

// ---- main kernels ----
__global__ __launch_bounds__(256) void transpose_kernel(const float* __restrict__ in,
                                                        float* __restrict__ out) {
  const int b = blockIdx.y;
  const int x = blockIdx.x * 256 + threadIdx.x;
  const float* __restrict__ ib = in + (size_t)b * NCH * LL;
  float* __restrict__ ob = out + (size_t)b * NCH * LL;
  float v[NCH];
#pragma unroll
  for (int c = 0; c < NCH; ++c) v[c] = ib[c * LL + x];
#pragma unroll
  for (int c = 0; c < NCH; c += 4)
    *(float4*)(ob + (size_t)x * NCH + c) = make_float4(v[c], v[c+1], v[c+2], v[c+3]);
}

__global__ __launch_bounds__(256)
void multistep_kernel(
    const float* __restrict__ zin,   // fp32 transposed [b][x][ch]
    float* __restrict__ zout,        // fp32 transposed (row-major if finalKer)
    const int* __restrict__ tptr, int finalKer)
{
  __shared__ __align__(16) __bf16 ISL[ISLAB * NCH];    // fused-conv slab
  __shared__ __align__(16) float  XW[DWIN];            // edge-fix x window

  const int b = blockIdx.y, bx = blockIdx.x;
  const int tid = threadIdx.x, lane = tid & 63, wv = tid >> 6;
  const int g = lane >> 4, n = lane & 15;

  const float* __restrict__ zb = zin + (size_t)b * NCH * LL;
  float* __restrict__ ob = zout + (size_t)b * NCH * LL;

  if (bx < NBX) {
    // ---- fused path: z' = z + S5 z (all 64 blocks; edges skip bad cols) ----
    const int x0 = bx * TX;
    const bool leftE = (bx == 0), rightE = (bx == NBX - 1);

    for (int q = tid; q < ISLAB * 4; q += 256) {
      const int s = q >> 2, cg = (q & 3) * 4;
      int gx = x0 - RAD + s;
      gx = min(max(gx, 0), LL - 1);     // only edge blocks clamp; bad cols skipped
      const float4 v = *(const float4*)(zb + (size_t)gx * NCH + cg);
      bf16x4 bv = { (__bf16)v.x, (__bf16)v.y, (__bf16)v.z, (__bf16)v.w };
      *(bf16x4*)(&ISL[ldsIdx(s, cg)]) = bv;
    }

    const int o0 = 16 * wv + n;                 // tiles wv and wv+4
    const f32x4 kz0 = *(const f32x4*)(zb + (size_t)(x0 + o0) * NCH + g * 4);
    const f32x4 kz1 = *(const f32x4*)(zb + (size_t)(x0 + o0 + 64) * NCH + g * 4);
    __syncthreads();

    const int p = g >> 1, hsel = g & 1;
    f32x4 acc0 = {0.f,0.f,0.f,0.f}, acc1 = acc0;
    const __bf16* Af = g_Sfrag + (size_t)lane * 8;
    int col0 = o0 + p;
#pragma unroll
    for (int c = 0; c < NCHUNK; ++c) {
      const bf16x8 a = *(const bf16x8*)(Af + (size_t)c * 512);
      const int xr = ((((col0 >> 2) & 1) ^ hsel) << 4);
      const bf16x8 b0 = *(const bf16x8*)((const char*)ISL + col0 * 32 + xr);
      const bf16x8 b1 = *(const bf16x8*)((const char*)ISL + (col0 + 64) * 32 + xr);
      acc0 = __builtin_amdgcn_mfma_f32_16x16x32_bf16(a, b0, acc0, 0, 0, 0);
      acc1 = __builtin_amdgcn_mfma_f32_16x16x32_bf16(a, b1, acc1, 0, 0, 0);
      col0 += 2;
    }

    f32x4 v0, v1;
#pragma unroll
    for (int r = 0; r < 4; ++r) { v0[r] = kz0[r] + acc0[r]; v1[r] = kz1[r] + acc1[r]; }

    // contaminated cols handled by edge-fix blocks: skip their stores
    const bool st0 = !(leftE && o0 <= 36);                  // v0 col = o0
    const bool st1 = !(rightE && o0 >= 27);                 // v1 col = o0+64 >= 91
    if (!finalKer) {
      if (st0) *(f32x4*)(ob + (size_t)(x0 + o0) * NCH + g * 4) = v0;
      if (st1) *(f32x4*)(ob + (size_t)(x0 + o0 + 64) * NCH + g * 4) = v1;
    } else {
#pragma unroll
      for (int r = 0; r < 4; ++r) {
        if (st0) ob[(size_t)(g * 4 + r) * LL + (x0 + o0)] = v0[r];
        if (st1) ob[(size_t)(g * 4 + r) * LL + (x0 + o0 + 64)] = v1[r];
      }
    }
  } else {
    // ---- edge-fix: out = x + C * x_win on contaminated cols ----
    const int q = bx - NBX;              // 0..3
    const int e = q >> 1, half = q & 1;
    const float* __restrict__ xs = zb + (e ? (size_t)(LL - 67) * NCH : 0);
    for (int i = tid; i < DWIN; i += 256) XW[i] = xs[i];
    __syncthreads();

    const int rbase = half * (NROWS / 2);
    const float* __restrict__ C = (e ? g_CR : g_CL) + (size_t)rbase * DWIN;
    for (int r = tid; r < NROWS / 2; r += 256) {
      const float* __restrict__ Crow = C + (size_t)r * DWIN;
      float acc = 0.f;
#pragma unroll 4
      for (int jj = 0; jj < DWIN; jj += 4) {
        const f32x4 cf = *(const f32x4*)(Crow + jj);
        const f32x4 xv = *(const f32x4*)(&XW[jj]);
        acc += cf[0]*xv[0] + cf[1]*xv[1] + cf[2]*xv[2] + cf[3]*xv[3];
      }
      const int row = rbase + r;         // row = local_col*16 + ch
      const float out = XW[(e ? 480 : 0) + row] + acc;
      if (e == 0) {
        if (!finalKer) ob[row] = out;
        else ob[(size_t)(row & 15) * LL + (row >> 4)] = out;
      } else {
        if (!finalKer) ob[(size_t)(LL - 37) * NCH + row] = out;
        else ob[(size_t)(row & 15) * LL + (LL - 37 + (row >> 4))] = out;
      }
    }
  }
}

extern "C" void kernel_launch(void* const* d_in, const int* in_sizes, int n_in,
                              void* d_out, int out_size, void* d_ws, size_t ws_size,
                              hipStream_t stream) {
  const float* z0 = (const float*)d_in[0];
  const float* W  = (const float*)d_in[1];
  const int*   t  = (const int*)d_in[2];

  float* Q = (float*)d_out;   // transposed intermediate; final row-major dest
  float* P = (float*)d_ws;    // 16 MiB scratch

  // Build S5 taps (interior operator).
  build_G<<<dim3(1), dim3(256), 0, stream>>>(W, t);
  compose_k<<<dim3( 9), dim3(256), 0, stream>>>(0);   // G2 = G*G
  compose_k<<<dim3(13), dim3(256), 0, stream>>>(1);   // G3 = G2*G -> g_Tp
  build_Tp<<<dim3(1), dim3(256), 0, stream>>>();      // T' = G + G2/2 + G3/6
  compose_k<<<dim3(25), dim3(256), 0, stream>>>(2);   // T'^2
  compose_k<<<dim3(37), dim3(256), 0, stream>>>(3);   // T'^3
  compose_k<<<dim3(49), dim3(256), 0, stream>>>(4);   // T'^4
  compose_k<<<dim3(61), dim3(256), 0, stream>>>(5);   // T'^5
  pack_S<<<dim3(NCHUNK), dim3(256), 0, stream>>>();

  // Build edge correction operators C_L/C_R (one-time, independent blocks).
  edge_evolve<<<dim3(DWIN, 2), dim3(384), 0, stream>>>(W, t);

  dim3 block(256);
  transpose_kernel<<<dim3(32, NB), block, 0, stream>>>(z0, Q);

  dim3 mgrid(NBX + EBLK, NB);
  for (int k = 1; k <= NKER; ++k) {
    if (k & 1) multistep_kernel<<<mgrid, block, 0, stream>>>(Q, P, t, 0);
    else       multistep_kernel<<<mgrid, block, 0, stream>>>(P, Q, t, k == NKER);
  }
}

// Round 5
// 1223.794 us; speedup vs baseline: 1.3514x; 1.3514x over previous
//
#include <hip/hip_runtime.h>

// NeuralODE SSP-RK3, z:[32,16,8192] fp32, W:[16,16,5], 100 steps, h=t/100.
// R15: interior fused to ONE 61-tap conv (z' = z + S5 z). R16: edges fused to
// out = x + C*x_win (C built on device by evolving basis vectors through the
// verified 15-stage code) -- PASSED but regressed to 96us/dispatch: the
// per-batch scalar GEMV read C uncoalesced (thread-per-row, lanes 4288B
// apart) and re-read C x32 batches, at 11% occupancy. Pure latency bind.
// R17 CHANGE: apply C as a small MFMA GEMM over the batch dimension.
// Out[592 x 32] = C[592x1072] . X[1072x32] per side: X in the A operand
// (A[m=batch][k], lanes read their batch's contiguous fp32 window from zin,
// cvt bf16 in-reg -- coalesced), C in the B operand pre-packed at setup into
// exact B-frag order (g_Cpack: one wave read = 1KB contiguous). Zero LDS in
// the edge path; ~50 live VGPRs (no spill at the pinned-64 budget); 26 waves
// in 7 rider blocks (bx==NBX). C read once per dispatch, not x32.
// Predicted: dispatch 96 -> 12-18us, total -> ~450us, absmax ~same.

#define NCH    16
#define LL     8192
#define TX     128
#define NBX    64
#define NB     32
#define NSTEPS 100
#define SPK    5
#define NKER   (NSTEPS / SPK)

#define RAD    30           // fused-operator radius = 6*SPK
#define NCHUNK 31           // 62 taps (61 real + 1 zero pad) / 2 per K-chunk
#define ISLAB  190          // interior slab cols: o(0..127)+k(0..61) -> 0..188

#define WCOLS  96           // edge-operator build window (6 MFMA tiles)
#define DWIN   1072         // 67 cols x 16 ch operator input dim
#define NROWS  592          // 37 cols x 16 ch contaminated outputs
#define NMT    37           // 592/16 m-tiles per side
#define NKC    34           // ceil(1072/32) K-chunks (padded to 1088)

typedef __bf16 bf16x8 __attribute__((ext_vector_type(8)));
typedef __bf16 bf16x4 __attribute__((ext_vector_type(4)));
typedef float  f32x4  __attribute__((ext_vector_type(4)));

// ---- setup: conv-kernel algebra in __device__ globals (fp32) ----
__device__ __align__(16) float g_G [ 5*256];   // h*F
__device__ __align__(16) float g_G2[ 9*256];   // G^2
__device__ __align__(16) float g_Tp[13*256];   // first G^3, then T'
__device__ __align__(16) float g_T2[25*256];   // T'^2
__device__ __align__(16) float g_T3[37*256];   // T'^3
__device__ __align__(16) float g_T4[49*256];   // T'^4
__device__ __align__(16) float g_T5[61*256];   // T'^5
__device__ __align__(16) __bf16 g_Sfrag[NCHUNK*64*8];  // A-frag table [c][lane][8]
__device__ __align__(16) float g_CL[(size_t)NROWS*DWIN];  // left  edge: M - I
__device__ __align__(16) float g_CR[(size_t)NROWS*DWIN];  // right edge: M - I
__device__ __align__(16) __bf16 g_Cpack[2][NMT][NKC][512]; // B-frag packed C

__global__ void build_G(const float* __restrict__ W, const int* __restrict__ tptr) {
  const float h = (float)(*tptr) / (float)NSTEPS;
  const int o = threadIdx.x >> 4, i = threadIdx.x & 15;
#pragma unroll
  for (int k = 0; k < 5; ++k)
    g_G[k*256 + o*16 + i] = h * W[o*80 + i*5 + k];
}

// C_d = sum_{a+b=d} A_a * B_b (16x16 matrix product per pair). grid.x = 2*(ra+rb)+1.
__global__ void compose_k(int mode) {
  const float* A; int ra; const float* B; int rb; float* C;
  switch (mode) {
    case 0:  A = g_G;  ra = 2;  B = g_G;  rb = 2; C = g_G2; break; //  9 taps
    case 1:  A = g_G2; ra = 4;  B = g_G;  rb = 2; C = g_Tp; break; // G^3, 13
    case 2:  A = g_Tp; ra = 6;  B = g_Tp; rb = 6; C = g_T2; break; // 25
    case 3:  A = g_T2; ra = 12; B = g_Tp; rb = 6; C = g_T3; break; // 37
    case 4:  A = g_T3; ra = 18; B = g_Tp; rb = 6; C = g_T4; break; // 49
    default: A = g_T4; ra = 24; B = g_Tp; rb = 6; C = g_T5; break; // 61
  }
  const int rc = ra + rb;
  const int d = (int)blockIdx.x - rc;
  const int o = threadIdx.x >> 4, i = threadIdx.x & 15;
  float acc = 0.f;
  for (int a = -ra; a <= ra; ++a) {
    const int b = d - a;
    if (b < -rb || b > rb) continue;
    const float* Am = A + (a+ra)*256 + o*16;
    const float* Bm = B + (b+rb)*256 + i;
#pragma unroll
    for (int j = 0; j < 16; ++j) acc += Am[j] * Bm[j*16];
  }
  C[(size_t)blockIdx.x*256 + o*16 + i] = acc;
}

__global__ void build_Tp() {   // g_Tp holds G^3; T' = G^3/6 + pad(G2)/2 + pad(G)
  const int o = threadIdx.x >> 4, i = threadIdx.x & 15;
#pragma unroll
  for (int k = 0; k < 13; ++k) {
    const int d = k - 6;
    float v = g_Tp[k*256 + o*16 + i] * (1.f/6.f);
    if (d >= -4 && d <= 4) v += 0.5f * g_G2[(d+4)*256 + o*16 + i];
    if (d >= -2 && d <= 2) v += g_G[(d+2)*256 + o*16 + i];
    g_Tp[k*256 + o*16 + i] = v;
  }
}

__device__ __forceinline__ float padread(const float* M, int r, int d, int oi) {
  return (d >= -r && d <= r) ? M[(d+r)*256 + oi] : 0.f;
}

// S5 = 5T' + 10T'^2 + 10T'^3 + 5T'^4 + T'^5, packed as bf16 MFMA A-frags.
__global__ void pack_S() {
  const int c = blockIdx.x;
  const int lane = threadIdx.x & 63;
  const int jj = (threadIdx.x >> 6) * 2;
  const int gg = lane >> 4, n = lane & 15;
  const int k = 2*c + (gg >> 1);
  const int d = k - RAD;
#pragma unroll
  for (int u = 0; u < 2; ++u) {
    const int j = jj + u;
    const int i = (gg & 1)*8 + j;
    const int oi = n*16 + i;
    float v = 0.f;
    if (k <= 60) {
      v = 5.f  * padread(g_Tp,  6, d, oi)
        + 10.f * padread(g_T2, 12, d, oi)
        + 10.f * padread(g_T3, 18, d, oi)
        + 5.f  * padread(g_T4, 24, d, oi)
        +        padread(g_T5, 30, d, oi);
    }
    g_Sfrag[((size_t)c*64 + lane)*8 + j] = (__bf16)v;
  }
}

// Pack C (fp32 [row][k]) -> bf16 B-frag order: g_Cpack[e][mt][kc][lane*8+j]
// = C[mt*16 + (lane&15)][kc*32 + (lane>>4)*8 + j], zero for k >= DWIN.
__global__ void pack_C() {
  const int mt = blockIdx.x, e = blockIdx.y;
  const float* __restrict__ C = e ? g_CR : g_CL;
  __bf16* __restrict__ P = &g_Cpack[e][mt][0][0];
  for (int idx = threadIdx.x; idx < NKC * 512; idx += 256) {
    const int kc = idx >> 9, q = idx & 511;
    const int ln = q >> 3, j = q & 7;
    const int k = kc * 32 + (ln >> 4) * 8 + j;
    const int row = mt * 16 + (ln & 15);
    P[idx] = (__bf16)((k < DWIN) ? C[(size_t)row * DWIN + k] : 0.f);
  }
}

// ---- shared helpers ----
__device__ __forceinline__ int ldsIdx(int col, int ch) {
  return col * NCH + (ch ^ ((col & 4) << 1));
}

__device__ __forceinline__ bf16x8 mkA(const float* __restrict__ W, int c, int g, int n) {
  const int kk = c * 2 + (g >> 1);
  bf16x8 a;
#pragma unroll
  for (int j = 0; j < 8; ++j) {
    const int i = (g & 1) * 8 + j;
    a[j] = (__bf16)((kk < 5) ? W[n * (NCH * 5) + i * 5 + kk] : 0.0f);
  }
  return a;
}

// ---- edge operator build: evolve basis vector j through 15 stages ----
__global__ __launch_bounds__(384)
void edge_evolve(const float* __restrict__ W, const int* __restrict__ tptr) {
  __shared__ __align__(16) __bf16 ES[2][WCOLS * NCH];
  const int j = blockIdx.x, e = blockIdx.y;
  const float h = (float)(*tptr) / (float)NSTEPS;
  const int tid = threadIdx.x, lane = tid & 63, wv = tid >> 6;  // wv 0..5
  const int g = lane >> 4, n = lane & 15;
  const int t = wv, mycol = 16 * t + n;
  const int cwj = (e ? 29 : 0) + (j >> 4), chj = j & 15;

  const bf16x8 af0 = mkA(W, 0, g, n);
  const bf16x8 af1 = mkA(W, 1, g, n);
  const bf16x8 af2 = mkA(W, 2, g, n);

  const int hot = ldsIdx(cwj, chj);
  for (int q = tid; q < WCOLS * NCH; q += 384)
    ES[0][q] = (__bf16)(q == hot ? 1.f : 0.f);

  f32x4 kz = {0.f, 0.f, 0.f, 0.f};
  if (mycol == cwj && g == (chj >> 2)) kz[chj & 3] = 1.f;
  f32x4 kf = {0.f, 0.f, 0.f, 0.f};
  __syncthreads();

  const float c13 = 1.0f / 3.0f, c23 = 2.0f / 3.0f;
  int rb = 0;
#pragma unroll 1
  for (int sp = 0; sp < SPK; ++sp) {
#pragma unroll 1
    for (int st = 0; st < 3; ++st) {
      const float az  = (st == 0) ? 1.0f : (st == 1) ? 0.75f : c13;
      const float ak  = (st == 0) ? 0.0f : (st == 1) ? 0.25f : c23;
      const float agh = (st == 0) ? h    : (st == 1) ? 0.25f*h : c23*h;
      const __bf16* RS = ES[rb];
      __bf16* WS = ES[rb ^ 1];
      f32x4 acc = {0.f, 0.f, 0.f, 0.f};
#pragma unroll
      for (int c = 0; c < 3; ++c) {
        const int kk = c * 2 + (g >> 1);
        int s = mycol + kk - 2;
        s = min(max(s, 0), WCOLS - 1);
        const bf16x8 bfrag = *(const bf16x8*)(&RS[ldsIdx(s, (g & 1) * 8)]);
        const bf16x8 a = (c == 0) ? af0 : (c == 1) ? af1 : af2;
        acc = __builtin_amdgcn_mfma_f32_16x16x32_bf16(a, bfrag, acc, 0, 0, 0);
      }
      f32x4 v;
#pragma unroll
      for (int r = 0; r < 4; ++r) v[r] = az * kz[r] + ak * kf[r] + agh * acc[r];
      if (e == 0 && t == 0) {            // cols 0..9 <- col 10
#pragma unroll
        for (int r = 0; r < 4; ++r) {
          const float sv = __shfl(v[r], (lane & 48) | 10, 64);
          if (n < 10) v[r] = sv;
        }
      }
      if (e == 1 && t == 5) {            // window cols 86..95 <- 85 (n=5)
#pragma unroll
        for (int r = 0; r < 4; ++r) {
          const float sv = __shfl(v[r], (lane & 48) | 5, 64);
          if (n > 5) v[r] = sv;
        }
      }
      kf = v;
      if (st == 2) kz = v;
      bf16x4 bv = { (__bf16)v[0], (__bf16)v[1], (__bf16)v[2], (__bf16)v[3] };
      *(bf16x4*)(&WS[ldsIdx(mycol, g * 4)]) = bv;
      __syncthreads();
      rb ^= 1;
    }
  }

  // extract contaminated rows of (M - I)
  if (e == 0) {
    if (mycol <= 36) {
      const int rowb = mycol * 16 + g * 4;
#pragma unroll
      for (int r = 0; r < 4; ++r) {
        const float id = (mycol == cwj && (g * 4 + r) == chj) ? 1.f : 0.f;
        g_CL[(size_t)(rowb + r) * DWIN + j] = kz[r] - id;
      }
    }
  } else {
    if (mycol >= 59) {                   // window 59..95 = global LL-37..LL-1
      const int rowb = (mycol - 59) * 16 + g * 4;
#pragma unroll
      for (int r = 0; r < 4; ++r) {
        const float id = (mycol == cwj && (g * 4 + r) == chj) ? 1.f : 0.f;
        g_CR[(size_t)(rowb + r) * DWIN + j] = kz[r] - id;
      }
    }
  }
}

// ---- main kernels ----
__global__ __launch_bounds__(256) void transpose_kernel(const float* __restrict__ in,
                                                        float* __restrict__ out) {
  const int b = blockIdx.y;
  const int x = blockIdx.x * 256 + threadIdx.x;
  const float* __restrict__ ib = in + (size_t)b * NCH * LL;
  float* __restrict__ ob = out + (size_t)b * NCH * LL;
  float v[NCH];
#pragma unroll
  for (int c = 0; c < NCH; ++c) v[c] = ib[c * LL + x];
#pragma unroll
  for (int c = 0; c < NCH; c += 4)
    *(float4*)(ob + (size_t)x * NCH + c) = make_float4(v[c], v[c+1], v[c+2], v[c+3]);
}

__global__ __launch_bounds__(256)
void multistep_kernel(
    const float* __restrict__ zin,   // fp32 transposed [b][x][ch]
    float* __restrict__ zout,        // fp32 transposed (row-major if finalKer)
    const int* __restrict__ tptr, int finalKer)
{
  __shared__ __align__(16) __bf16 ISL[ISLAB * NCH];    // fused-conv slab

  const int b = blockIdx.y, bx = blockIdx.x;
  const int tid = threadIdx.x, lane = tid & 63, wv = tid >> 6;
  const int g = lane >> 4, n = lane & 15;

  if (bx < NBX) {
    // ---- fused path: z' = z + S5 z (all 64 blocks; edges skip bad cols) ----
    const float* __restrict__ zb = zin + (size_t)b * NCH * LL;
    float* __restrict__ ob = zout + (size_t)b * NCH * LL;
    const int x0 = bx * TX;
    const bool leftE = (bx == 0), rightE = (bx == NBX - 1);

    for (int q = tid; q < ISLAB * 4; q += 256) {
      const int s = q >> 2, cg = (q & 3) * 4;
      int gx = x0 - RAD + s;
      gx = min(max(gx, 0), LL - 1);     // only edge blocks clamp; bad cols skipped
      const float4 v = *(const float4*)(zb + (size_t)gx * NCH + cg);
      bf16x4 bv = { (__bf16)v.x, (__bf16)v.y, (__bf16)v.z, (__bf16)v.w };
      *(bf16x4*)(&ISL[ldsIdx(s, cg)]) = bv;
    }

    const int o0 = 16 * wv + n;                 // tiles wv and wv+4
    const f32x4 kz0 = *(const f32x4*)(zb + (size_t)(x0 + o0) * NCH + g * 4);
    const f32x4 kz1 = *(const f32x4*)(zb + (size_t)(x0 + o0 + 64) * NCH + g * 4);
    __syncthreads();

    const int p = g >> 1, hsel = g & 1;
    f32x4 acc0 = {0.f,0.f,0.f,0.f}, acc1 = acc0;
    const __bf16* Af = g_Sfrag + (size_t)lane * 8;
    int col0 = o0 + p;
#pragma unroll
    for (int c = 0; c < NCHUNK; ++c) {
      const bf16x8 a = *(const bf16x8*)(Af + (size_t)c * 512);
      const int xr = ((((col0 >> 2) & 1) ^ hsel) << 4);
      const bf16x8 b0 = *(const bf16x8*)((const char*)ISL + col0 * 32 + xr);
      const bf16x8 b1 = *(const bf16x8*)((const char*)ISL + (col0 + 64) * 32 + xr);
      acc0 = __builtin_amdgcn_mfma_f32_16x16x32_bf16(a, b0, acc0, 0, 0, 0);
      acc1 = __builtin_amdgcn_mfma_f32_16x16x32_bf16(a, b1, acc1, 0, 0, 0);
      col0 += 2;
    }

    f32x4 v0, v1;
#pragma unroll
    for (int r = 0; r < 4; ++r) { v0[r] = kz0[r] + acc0[r]; v1[r] = kz1[r] + acc1[r]; }

    // contaminated cols handled by edge-GEMM blocks: skip their stores
    const bool st0 = !(leftE && o0 <= 36);                  // v0 col = o0
    const bool st1 = !(rightE && o0 >= 27);                 // v1 col = o0+64 >= 91
    if (!finalKer) {
      if (st0) *(f32x4*)(ob + (size_t)(x0 + o0) * NCH + g * 4) = v0;
      if (st1) *(f32x4*)(ob + (size_t)(x0 + o0 + 64) * NCH + g * 4) = v1;
    } else {
#pragma unroll
      for (int r = 0; r < 4; ++r) {
        if (st0) ob[(size_t)(g * 4 + r) * LL + (x0 + o0)] = v0[r];
        if (st1) ob[(size_t)(g * 4 + r) * LL + (x0 + o0 + 64)] = v1[r];
      }
    }
  } else {
    // ---- edge GEMM riders (bx == NBX): Out = C . X over all batches ----
    // Wave task: side in {0,1}, 3 m-tiles. A[m=batch][k] = X (fp32->bf16 in
    // reg, coalesced); B[k][row] = g_Cpack (frag-packed, 1KB/wave reads).
    const int task = b * 4 + wv;                // b = blockIdx.y reused as id
    if (task >= 26) return;                     // 2 sides x 13 waves
    const int side = task / 13, ws = task % 13;
    const size_t woff = side ? (size_t)(LL - 67) * NCH : 0;
    const __bf16* __restrict__ Cp = &g_Cpack[side][0][0][0];

    f32x4 accA[3], accB[3];
#pragma unroll
    for (int i = 0; i < 3; ++i) {
      accA[i] = {0.f,0.f,0.f,0.f}; accB[i] = {0.f,0.f,0.f,0.f};
    }

    const float* __restrict__ xw0 = zin + (size_t)n * NCH * LL + woff;
    const float* __restrict__ xw1 = zin + (size_t)(n + 16) * NCH * LL + woff;

#pragma unroll 2
    for (int kc = 0; kc < NKC; ++kc) {
      const int k = kc * 32 + g * 8;
      bf16x8 a0, a1;
      if (k < DWIN) {
        const f32x4 xa0 = *(const f32x4*)(xw0 + k);
        const f32x4 xb0 = *(const f32x4*)(xw0 + k + 4);
        const f32x4 xa1 = *(const f32x4*)(xw1 + k);
        const f32x4 xb1 = *(const f32x4*)(xw1 + k + 4);
#pragma unroll
        for (int j = 0; j < 4; ++j) {
          a0[j] = (__bf16)xa0[j]; a0[4+j] = (__bf16)xb0[j];
          a1[j] = (__bf16)xa1[j]; a1[4+j] = (__bf16)xb1[j];
        }
      } else {
#pragma unroll
        for (int j = 0; j < 8; ++j) { a0[j] = (__bf16)0.f; a1[j] = (__bf16)0.f; }
      }
#pragma unroll
      for (int i = 0; i < 3; ++i) {
        const int mtg = ws * 3 + i;
        if (mtg >= NMT) continue;
        const bf16x8 bfr = *(const bf16x8*)(Cp + ((size_t)mtg * NKC + kc) * 512 + lane * 8);
        accA[i] = __builtin_amdgcn_mfma_f32_16x16x32_bf16(a0, bfr, accA[i], 0, 0, 0);
        accB[i] = __builtin_amdgcn_mfma_f32_16x16x32_bf16(a1, bfr, accB[i], 0, 0, 0);
      }
    }

    // store: lane(g,n) holds D[batch=4g+r][row = mt*16+n]; row -> (x, ch=n)
#pragma unroll
    for (int i = 0; i < 3; ++i) {
      const int mtg = ws * 3 + i;
      if (mtg >= NMT) continue;
      const int x = side ? (LL - 37 + mtg) : mtg;
#pragma unroll
      for (int r = 0; r < 4; ++r) {
        const int bb0 = 4 * g + r, bb1 = bb0 + 16;
        const size_t base0 = (size_t)bb0 * NCH * LL, base1 = (size_t)bb1 * NCH * LL;
        const float o0v = zin[base0 + (size_t)x * NCH + n] + accA[i][r];
        const float o1v = zin[base1 + (size_t)x * NCH + n] + accB[i][r];
        if (!finalKer) {
          zout[base0 + (size_t)x * NCH + n] = o0v;
          zout[base1 + (size_t)x * NCH + n] = o1v;
        } else {
          zout[base0 + (size_t)n * LL + x] = o0v;
          zout[base1 + (size_t)n * LL + x] = o1v;
        }
      }
    }
  }
}

extern "C" void kernel_launch(void* const* d_in, const int* in_sizes, int n_in,
                              void* d_out, int out_size, void* d_ws, size_t ws_size,
                              hipStream_t stream) {
  const float* z0 = (const float*)d_in[0];
  const float* W  = (const float*)d_in[1];
  const int*   t  = (const int*)d_in[2];

  float* Q = (float*)d_out;   // transposed intermediate; final row-major dest
  float* P = (float*)d_ws;    // 16 MiB scratch

  // Build S5 taps (interior operator).
  build_G<<<dim3(1), dim3(256), 0, stream>>>(W, t);
  compose_k<<<dim3( 9), dim3(256), 0, stream>>>(0);   // G2 = G*G
  compose_k<<<dim3(13), dim3(256), 0, stream>>>(1);   // G3 = G2*G -> g_Tp
  build_Tp<<<dim3(1), dim3(256), 0, stream>>>();      // T' = G + G2/2 + G3/6
  compose_k<<<dim3(25), dim3(256), 0, stream>>>(2);   // T'^2
  compose_k<<<dim3(37), dim3(256), 0, stream>>>(3);   // T'^3
  compose_k<<<dim3(49), dim3(256), 0, stream>>>(4);   // T'^4
  compose_k<<<dim3(61), dim3(256), 0, stream>>>(5);   // T'^5
  pack_S<<<dim3(NCHUNK), dim3(256), 0, stream>>>();

  // Build + pack edge correction operators (one-time).
  edge_evolve<<<dim3(DWIN, 2), dim3(384), 0, stream>>>(W, t);
  pack_C<<<dim3(NMT, 2), dim3(256), 0, stream>>>();

  dim3 block(256);
  transpose_kernel<<<dim3(32, NB), block, 0, stream>>>(z0, Q);

  dim3 mgrid(NBX + 1, NB);
  for (int k = 1; k <= NKER; ++k) {
    if (k & 1) multistep_kernel<<<mgrid, block, 0, stream>>>(Q, P, t, 0);
    else       multistep_kernel<<<mgrid, block, 0, stream>>>(P, Q, t, k == NKER);
  }
}

// Round 7
// 789.213 us; speedup vs baseline: 2.0955x; 1.5507x over previous
//
#include <hip/hip_runtime.h>

// NeuralODE SSP-RK3, z:[32,16,8192] fp32, W:[16,16,5], 100 steps, h=t/100.
// R15: interior fused to ONE 61-tap conv (z' = z + S5 z). R16/R17: edges
// fused to out = x + C*x_win, applied as MFMA GEMM over batch (C in B-frags,
// packed at setup). R17 post-mortem (56.7us/dispatch, occ 9.5%): straggler =
// rider path again -- only 26 waves carried the edge GEMM and the A-operand
// X loads were a 512KB-strided gather (lane n = batch n), ~16 cache lines
// per 16B load with no TLP to hide misses.
// R18 CHANGE: use ALL 32 rider blocks (side, bhalf, mseg) = (rid&1,
// (rid>>1)&1, rid>>2); each block stages its 16-batch X window into LDS with
// COALESCED f32x4 reads (window contiguous per batch), bf16, stride 1096;
// each wave then runs 1-2 m-tiles x 34 kc of {1 ds_read_b128 A-frag + 1KB
// coalesced Cp load + MFMA}. 128 rider waves, ~34 LDS-bound iters each.
// LDS = 35KB union (interior uses 6KB; 4 blocks/CU residency, 16 waves/CU).
// R19: RESUBMIT of R18 unchanged -- bench failed with "MI355X container
// failed twice" (infra, no compile/test/profile output). Kernel re-audited
// for OOB/alignment/LDS overflow: none found.
// Predicted: dispatch 56.7 -> 14-20us, occ -> 25-40%, total -> ~450us.

#define NCH    16
#define LL     8192
#define TX     128
#define NBX    64
#define NB     32
#define NSTEPS 100
#define SPK    5
#define NKER   (NSTEPS / SPK)

#define RAD    30           // fused-operator radius = 6*SPK
#define NCHUNK 31           // 62 taps (61 real + 1 zero pad) / 2 per K-chunk
#define ISLAB  190          // interior slab cols: o(0..127)+k(0..61) -> 0..188

#define WCOLS  96           // edge-operator build window (6 MFMA tiles)
#define DWIN   1072         // 67 cols x 16 ch operator input dim
#define NROWS  592          // 37 cols x 16 ch contaminated outputs
#define NMT    37           // 592/16 m-tiles per side
#define NKC    34           // ceil(1072/32) K-chunks (padded to 1088)
#define XSTR   1096         // LDS X row stride (bf16 elems; pad for banks)

typedef __bf16 bf16x8 __attribute__((ext_vector_type(8)));
typedef __bf16 bf16x4 __attribute__((ext_vector_type(4)));
typedef float  f32x4  __attribute__((ext_vector_type(4)));

// ---- setup: conv-kernel algebra in __device__ globals (fp32) ----
__device__ __align__(16) float g_G [ 5*256];   // h*F
__device__ __align__(16) float g_G2[ 9*256];   // G^2
__device__ __align__(16) float g_Tp[13*256];   // first G^3, then T'
__device__ __align__(16) float g_T2[25*256];   // T'^2
__device__ __align__(16) float g_T3[37*256];   // T'^3
__device__ __align__(16) float g_T4[49*256];   // T'^4
__device__ __align__(16) float g_T5[61*256];   // T'^5
__device__ __align__(16) __bf16 g_Sfrag[NCHUNK*64*8];  // A-frag table [c][lane][8]
__device__ __align__(16) float g_CL[(size_t)NROWS*DWIN];  // left  edge: M - I
__device__ __align__(16) float g_CR[(size_t)NROWS*DWIN];  // right edge: M - I
__device__ __align__(16) __bf16 g_Cpack[2][NMT][NKC][512]; // B-frag packed C

__global__ void build_G(const float* __restrict__ W, const int* __restrict__ tptr) {
  const float h = (float)(*tptr) / (float)NSTEPS;
  const int o = threadIdx.x >> 4, i = threadIdx.x & 15;
#pragma unroll
  for (int k = 0; k < 5; ++k)
    g_G[k*256 + o*16 + i] = h * W[o*80 + i*5 + k];
}

// C_d = sum_{a+b=d} A_a * B_b (16x16 matrix product per pair). grid.x = 2*(ra+rb)+1.
__global__ void compose_k(int mode) {
  const float* A; int ra; const float* B; int rb; float* C;
  switch (mode) {
    case 0:  A = g_G;  ra = 2;  B = g_G;  rb = 2; C = g_G2; break; //  9 taps
    case 1:  A = g_G2; ra = 4;  B = g_G;  rb = 2; C = g_Tp; break; // G^3, 13
    case 2:  A = g_Tp; ra = 6;  B = g_Tp; rb = 6; C = g_T2; break; // 25
    case 3:  A = g_T2; ra = 12; B = g_Tp; rb = 6; C = g_T3; break; // 37
    case 4:  A = g_T3; ra = 18; B = g_Tp; rb = 6; C = g_T4; break; // 49
    default: A = g_T4; ra = 24; B = g_Tp; rb = 6; C = g_T5; break; // 61
  }
  const int rc = ra + rb;
  const int d = (int)blockIdx.x - rc;
  const int o = threadIdx.x >> 4, i = threadIdx.x & 15;
  float acc = 0.f;
  for (int a = -ra; a <= ra; ++a) {
    const int b = d - a;
    if (b < -rb || b > rb) continue;
    const float* Am = A + (a+ra)*256 + o*16;
    const float* Bm = B + (b+rb)*256 + i;
#pragma unroll
    for (int j = 0; j < 16; ++j) acc += Am[j] * Bm[j*16];
  }
  C[(size_t)blockIdx.x*256 + o*16 + i] = acc;
}

__global__ void build_Tp() {   // g_Tp holds G^3; T' = G^3/6 + pad(G2)/2 + pad(G)
  const int o = threadIdx.x >> 4, i = threadIdx.x & 15;
#pragma unroll
  for (int k = 0; k < 13; ++k) {
    const int d = k - 6;
    float v = g_Tp[k*256 + o*16 + i] * (1.f/6.f);
    if (d >= -4 && d <= 4) v += 0.5f * g_G2[(d+4)*256 + o*16 + i];
    if (d >= -2 && d <= 2) v += g_G[(d+2)*256 + o*16 + i];
    g_Tp[k*256 + o*16 + i] = v;
  }
}

__device__ __forceinline__ float padread(const float* M, int r, int d, int oi) {
  return (d >= -r && d <= r) ? M[(d+r)*256 + oi] : 0.f;
}

// S5 = 5T' + 10T'^2 + 10T'^3 + 5T'^4 + T'^5, packed as bf16 MFMA A-frags.
__global__ void pack_S() {
  const int c = blockIdx.x;
  const int lane = threadIdx.x & 63;
  const int jj = (threadIdx.x >> 6) * 2;
  const int gg = lane >> 4, n = lane & 15;
  const int k = 2*c + (gg >> 1);
  const int d = k - RAD;
#pragma unroll
  for (int u = 0; u < 2; ++u) {
    const int j = jj + u;
    const int i = (gg & 1)*8 + j;
    const int oi = n*16 + i;
    float v = 0.f;
    if (k <= 60) {
      v = 5.f  * padread(g_Tp,  6, d, oi)
        + 10.f * padread(g_T2, 12, d, oi)
        + 10.f * padread(g_T3, 18, d, oi)
        + 5.f  * padread(g_T4, 24, d, oi)
        +        padread(g_T5, 30, d, oi);
    }
    g_Sfrag[((size_t)c*64 + lane)*8 + j] = (__bf16)v;
  }
}

// Pack C (fp32 [row][k]) -> bf16 B-frag order: g_Cpack[e][mt][kc][lane*8+j]
// = C[mt*16 + (lane&15)][kc*32 + (lane>>4)*8 + j], zero for k >= DWIN.
__global__ void pack_C() {
  const int mt = blockIdx.x, e = blockIdx.y;
  const float* __restrict__ C = e ? g_CR : g_CL;
  __bf16* __restrict__ P = &g_Cpack[e][mt][0][0];
  for (int idx = threadIdx.x; idx < NKC * 512; idx += 256) {
    const int kc = idx >> 9, q = idx & 511;
    const int ln = q >> 3, j = q & 7;
    const int k = kc * 32 + (ln >> 4) * 8 + j;
    const int row = mt * 16 + (ln & 15);
    P[idx] = (__bf16)((k < DWIN) ? C[(size_t)row * DWIN + k] : 0.f);
  }
}

// ---- shared helpers ----
__device__ __forceinline__ int ldsIdx(int col, int ch) {
  return col * NCH + (ch ^ ((col & 4) << 1));
}

__device__ __forceinline__ bf16x8 mkA(const float* __restrict__ W, int c, int g, int n) {
  const int kk = c * 2 + (g >> 1);
  bf16x8 a;
#pragma unroll
  for (int j = 0; j < 8; ++j) {
    const int i = (g & 1) * 8 + j;
    a[j] = (__bf16)((kk < 5) ? W[n * (NCH * 5) + i * 5 + kk] : 0.0f);
  }
  return a;
}

// ---- edge operator build: evolve basis vector j through 15 stages ----
__global__ __launch_bounds__(384)
void edge_evolve(const float* __restrict__ W, const int* __restrict__ tptr) {
  __shared__ __align__(16) __bf16 ES[2][WCOLS * NCH];
  const int j = blockIdx.x, e = blockIdx.y;
  const float h = (float)(*tptr) / (float)NSTEPS;
  const int tid = threadIdx.x, lane = tid & 63, wv = tid >> 6;  // wv 0..5
  const int g = lane >> 4, n = lane & 15;
  const int t = wv, mycol = 16 * t + n;
  const int cwj = (e ? 29 : 0) + (j >> 4), chj = j & 15;

  const bf16x8 af0 = mkA(W, 0, g, n);
  const bf16x8 af1 = mkA(W, 1, g, n);
  const bf16x8 af2 = mkA(W, 2, g, n);

  const int hot = ldsIdx(cwj, chj);
  for (int q = tid; q < WCOLS * NCH; q += 384)
    ES[0][q] = (__bf16)(q == hot ? 1.f : 0.f);

  f32x4 kz = {0.f, 0.f, 0.f, 0.f};
  if (mycol == cwj && g == (chj >> 2)) kz[chj & 3] = 1.f;
  f32x4 kf = {0.f, 0.f, 0.f, 0.f};
  __syncthreads();

  const float c13 = 1.0f / 3.0f, c23 = 2.0f / 3.0f;
  int rb = 0;
#pragma unroll 1
  for (int sp = 0; sp < SPK; ++sp) {
#pragma unroll 1
    for (int st = 0; st < 3; ++st) {
      const float az  = (st == 0) ? 1.0f : (st == 1) ? 0.75f : c13;
      const float ak  = (st == 0) ? 0.0f : (st == 1) ? 0.25f : c23;
      const float agh = (st == 0) ? h    : (st == 1) ? 0.25f*h : c23*h;
      const __bf16* RS = ES[rb];
      __bf16* WS = ES[rb ^ 1];
      f32x4 acc = {0.f, 0.f, 0.f, 0.f};
#pragma unroll
      for (int c = 0; c < 3; ++c) {
        const int kk = c * 2 + (g >> 1);
        int s = mycol + kk - 2;
        s = min(max(s, 0), WCOLS - 1);
        const bf16x8 bfrag = *(const bf16x8*)(&RS[ldsIdx(s, (g & 1) * 8)]);
        const bf16x8 a = (c == 0) ? af0 : (c == 1) ? af1 : af2;
        acc = __builtin_amdgcn_mfma_f32_16x16x32_bf16(a, bfrag, acc, 0, 0, 0);
      }
      f32x4 v;
#pragma unroll
      for (int r = 0; r < 4; ++r) v[r] = az * kz[r] + ak * kf[r] + agh * acc[r];
      if (e == 0 && t == 0) {            // cols 0..9 <- col 10
#pragma unroll
        for (int r = 0; r < 4; ++r) {
          const float sv = __shfl(v[r], (lane & 48) | 10, 64);
          if (n < 10) v[r] = sv;
        }
      }
      if (e == 1 && t == 5) {            // window cols 86..95 <- 85 (n=5)
#pragma unroll
        for (int r = 0; r < 4; ++r) {
          const float sv = __shfl(v[r], (lane & 48) | 5, 64);
          if (n > 5) v[r] = sv;
        }
      }
      kf = v;
      if (st == 2) kz = v;
      bf16x4 bv = { (__bf16)v[0], (__bf16)v[1], (__bf16)v[2], (__bf16)v[3] };
      *(bf16x4*)(&WS[ldsIdx(mycol, g * 4)]) = bv;
      __syncthreads();
      rb ^= 1;
    }
  }

  // extract contaminated rows of (M - I)
  if (e == 0) {
    if (mycol <= 36) {
      const int rowb = mycol * 16 + g * 4;
#pragma unroll
      for (int r = 0; r < 4; ++r) {
        const float id = (mycol == cwj && (g * 4 + r) == chj) ? 1.f : 0.f;
        g_CL[(size_t)(rowb + r) * DWIN + j] = kz[r] - id;
      }
    }
  } else {
    if (mycol >= 59) {                   // window 59..95 = global LL-37..LL-1
      const int rowb = (mycol - 59) * 16 + g * 4;
#pragma unroll
      for (int r = 0; r < 4; ++r) {
        const float id = (mycol == cwj && (g * 4 + r) == chj) ? 1.f : 0.f;
        g_CR[(size_t)(rowb + r) * DWIN + j] = kz[r] - id;
      }
    }
  }
}

// ---- main kernels ----
__global__ __launch_bounds__(256) void transpose_kernel(const float* __restrict__ in,
                                                        float* __restrict__ out) {
  const int b = blockIdx.y;
  const int x = blockIdx.x * 256 + threadIdx.x;
  const float* __restrict__ ib = in + (size_t)b * NCH * LL;
  float* __restrict__ ob = out + (size_t)b * NCH * LL;
  float v[NCH];
#pragma unroll
  for (int c = 0; c < NCH; ++c) v[c] = ib[c * LL + x];
#pragma unroll
  for (int c = 0; c < NCH; c += 4)
    *(float4*)(ob + (size_t)x * NCH + c) = make_float4(v[c], v[c+1], v[c+2], v[c+3]);
}

__global__ __launch_bounds__(256)
void multistep_kernel(
    const float* __restrict__ zin,   // fp32 transposed [b][x][ch]
    float* __restrict__ zout,        // fp32 transposed (row-major if finalKer)
    const int* __restrict__ tptr, int finalKer)
{
  // union: interior slab (6080B) | rider X stage (16 x XSTR bf16 = 35072B)
  __shared__ __align__(16) char SMEM[16 * XSTR * 2];

  const int b = blockIdx.y, bx = blockIdx.x;
  const int tid = threadIdx.x, lane = tid & 63, wv = tid >> 6;
  const int g = lane >> 4, n = lane & 15;

  if (bx < NBX) {
    // ---- fused path: z' = z + S5 z (all 64 blocks; edges skip bad cols) ----
    __bf16* __restrict__ ISL = (__bf16*)SMEM;
    const float* __restrict__ zb = zin + (size_t)b * NCH * LL;
    float* __restrict__ ob = zout + (size_t)b * NCH * LL;
    const int x0 = bx * TX;
    const bool leftE = (bx == 0), rightE = (bx == NBX - 1);

    for (int q = tid; q < ISLAB * 4; q += 256) {
      const int s = q >> 2, cg = (q & 3) * 4;
      int gx = x0 - RAD + s;
      gx = min(max(gx, 0), LL - 1);     // only edge blocks clamp; bad cols skipped
      const float4 v = *(const float4*)(zb + (size_t)gx * NCH + cg);
      bf16x4 bv = { (__bf16)v.x, (__bf16)v.y, (__bf16)v.z, (__bf16)v.w };
      *(bf16x4*)(&ISL[ldsIdx(s, cg)]) = bv;
    }

    const int o0 = 16 * wv + n;                 // tiles wv and wv+4
    const f32x4 kz0 = *(const f32x4*)(zb + (size_t)(x0 + o0) * NCH + g * 4);
    const f32x4 kz1 = *(const f32x4*)(zb + (size_t)(x0 + o0 + 64) * NCH + g * 4);
    __syncthreads();

    const int p = g >> 1, hsel = g & 1;
    f32x4 acc0 = {0.f,0.f,0.f,0.f}, acc1 = acc0;
    const __bf16* Af = g_Sfrag + (size_t)lane * 8;
    int col0 = o0 + p;
#pragma unroll
    for (int c = 0; c < NCHUNK; ++c) {
      const bf16x8 a = *(const bf16x8*)(Af + (size_t)c * 512);
      const int xr = ((((col0 >> 2) & 1) ^ hsel) << 4);
      const bf16x8 b0 = *(const bf16x8*)((const char*)ISL + col0 * 32 + xr);
      const bf16x8 b1 = *(const bf16x8*)((const char*)ISL + (col0 + 64) * 32 + xr);
      acc0 = __builtin_amdgcn_mfma_f32_16x16x32_bf16(a, b0, acc0, 0, 0, 0);
      acc1 = __builtin_amdgcn_mfma_f32_16x16x32_bf16(a, b1, acc1, 0, 0, 0);
      col0 += 2;
    }

    f32x4 v0, v1;
#pragma unroll
    for (int r = 0; r < 4; ++r) { v0[r] = kz0[r] + acc0[r]; v1[r] = kz1[r] + acc1[r]; }

    // contaminated cols handled by edge-GEMM riders: skip their stores
    const bool st0 = !(leftE && o0 <= 36);                  // v0 col = o0
    const bool st1 = !(rightE && o0 >= 27);                 // v1 col = o0+64 >= 91
    if (!finalKer) {
      if (st0) *(f32x4*)(ob + (size_t)(x0 + o0) * NCH + g * 4) = v0;
      if (st1) *(f32x4*)(ob + (size_t)(x0 + o0 + 64) * NCH + g * 4) = v1;
    } else {
#pragma unroll
      for (int r = 0; r < 4; ++r) {
        if (st0) ob[(size_t)(g * 4 + r) * LL + (x0 + o0)] = v0[r];
        if (st1) ob[(size_t)(g * 4 + r) * LL + (x0 + o0 + 64)] = v1[r];
      }
    }
  } else {
    // ---- edge GEMM riders (bx == NBX, 32 blocks) ----
    // rid -> (side, batch-half, m-segment). Block stages 16-batch X window
    // into LDS (coalesced: window contiguous per batch), then wave q =
    // mseg*4+wv computes m-tiles {q, q+32} x 34 kc: A-frag = ds_read_b128
    // (batch n, k = kc*32+g*8), B-frag = g_Cpack 16B/lane coalesced, MFMA.
    const int rid = b;
    const int side = rid & 1, bhalf = (rid >> 1) & 1, mseg = rid >> 2;
    __bf16* __restrict__ XL = (__bf16*)SMEM;          // [16][XSTR]
    const size_t woff = side ? (size_t)(LL - 67) * NCH : 0;

    for (int q = tid; q < 16 * 268; q += 256) {       // 268 f32x4 = 1072 fl
      const int bb = q / 268, c4 = q % 268;
      const f32x4 v = *(const f32x4*)(zin + (size_t)(bhalf*16 + bb) * NCH * LL
                                      + woff + c4 * 4);
      bf16x4 bv = { (__bf16)v[0], (__bf16)v[1], (__bf16)v[2], (__bf16)v[3] };
      *(bf16x4*)(&XL[bb * XSTR + c4 * 4]) = bv;
    }
    for (int q = tid; q < 16 * 16; q += 256)          // zero k pad 1072..1087
      XL[(q >> 4) * XSTR + 1072 + (q & 15)] = (__bf16)0.f;
    __syncthreads();

    const int q = mseg * 4 + wv;                      // 0..31
    const int mt0 = q, mt1 = q + 32;
    const bool has1 = (mt1 < NMT);
    f32x4 acc0 = {0.f,0.f,0.f,0.f}, acc1 = acc0;
    const __bf16* __restrict__ Cp = &g_Cpack[side][0][0][0];
    const __bf16* __restrict__ Xr = &XL[n * XSTR + g * 8];

#pragma unroll 2
    for (int kc = 0; kc < NKC; ++kc) {
      const bf16x8 a = *(const bf16x8*)(Xr + kc * 32);
      const bf16x8 b0 = *(const bf16x8*)(Cp + ((size_t)mt0 * NKC + kc) * 512 + lane * 8);
      acc0 = __builtin_amdgcn_mfma_f32_16x16x32_bf16(a, b0, acc0, 0, 0, 0);
      if (has1) {
        const bf16x8 b1 = *(const bf16x8*)(Cp + ((size_t)mt1 * NKC + kc) * 512 + lane * 8);
        acc1 = __builtin_amdgcn_mfma_f32_16x16x32_bf16(a, b1, acc1, 0, 0, 0);
      }
    }

    // D: lane(g,n) holds [batch = bhalf*16 + 4g+r][outrow = mt*16 + n];
    // outrow -> x = side ? LL-37+mt : mt (same for all n), ch = n.
#pragma unroll
    for (int i = 0; i < 2; ++i) {
      if (i == 1 && !has1) break;
      const int mt = i ? mt1 : mt0;
      const f32x4 acc = i ? acc1 : acc0;
      const int x = side ? (LL - 37 + mt) : mt;
#pragma unroll
      for (int r = 0; r < 4; ++r) {
        const int bb = bhalf * 16 + 4 * g + r;
        const size_t base = (size_t)bb * NCH * LL;
        const float ov = zin[base + (size_t)x * NCH + n] + acc[r];
        if (!finalKer) zout[base + (size_t)x * NCH + n] = ov;
        else           zout[base + (size_t)n * LL + x] = ov;
      }
    }
  }
}

extern "C" void kernel_launch(void* const* d_in, const int* in_sizes, int n_in,
                              void* d_out, int out_size, void* d_ws, size_t ws_size,
                              hipStream_t stream) {
  const float* z0 = (const float*)d_in[0];
  const float* W  = (const float*)d_in[1];
  const int*   t  = (const int*)d_in[2];

  float* Q = (float*)d_out;   // transposed intermediate; final row-major dest
  float* P = (float*)d_ws;    // 16 MiB scratch

  // Build S5 taps (interior operator).
  build_G<<<dim3(1), dim3(256), 0, stream>>>(W, t);
  compose_k<<<dim3( 9), dim3(256), 0, stream>>>(0);   // G2 = G*G
  compose_k<<<dim3(13), dim3(256), 0, stream>>>(1);   // G3 = G2*G -> g_Tp
  build_Tp<<<dim3(1), dim3(256), 0, stream>>>();      // T' = G + G2/2 + G3/6
  compose_k<<<dim3(25), dim3(256), 0, stream>>>(2);   // T'^2
  compose_k<<<dim3(37), dim3(256), 0, stream>>>(3);   // T'^3
  compose_k<<<dim3(49), dim3(256), 0, stream>>>(4);   // T'^4
  compose_k<<<dim3(61), dim3(256), 0, stream>>>(5);   // T'^5
  pack_S<<<dim3(NCHUNK), dim3(256), 0, stream>>>();

  // Build + pack edge correction operators (one-time).
  edge_evolve<<<dim3(DWIN, 2), dim3(384), 0, stream>>>(W, t);
  pack_C<<<dim3(NMT, 2), dim3(256), 0, stream>>>();

  dim3 block(256);
  transpose_kernel<<<dim3(32, NB), block, 0, stream>>>(z0, Q);

  dim3 mgrid(NBX + 1, NB);
  for (int k = 1; k <= NKER; ++k) {
    if (k & 1) multistep_kernel<<<mgrid, block, 0, stream>>>(Q, P, t, 0);
    else       multistep_kernel<<<mgrid, block, 0, stream>>>(P, Q, t, k == NKER);
  }
}